// Round 9
// baseline (333.546 us; speedup 1.0000x reference)
//
#include <hip/hip_runtime.h>

#define N_TR 1024
#define H_DIM 128
#define P_PAIRS 523776   // N*(N-1)/2
#define TI 8             // i-rows per block tile
#define N_BLOCKS 1088    // sum over jt<16 of 8*(jt+1); cum(jt)=4jt(jt+1)
// ws float offsets (f32 regions)
#define WS_U    0
#define WS_V    131072
#define WS_SUMU 393216   // per i: {sumU, sumU2} (cons net)
#define WS_SUMV 395264   // per j: {sumV, sumV2} (cons net, V includes bias)
// ws ushort offsets (f16 regions)
#define WS_UAH  524288   // Ua as f16, 1024x128
#define WS_VAH  655360   // Va as f16 (incl bias), 1024x128
// ws byte offsets
#define WS_FRAG_BYTES 1589248u  // 12288 ushorts: [0,8192) cons bf16, [8192,12288) assoc f16

typedef __attribute__((ext_vector_type(8))) short bf16x8;
typedef __attribute__((ext_vector_type(8))) _Float16 h16x8;
typedef __attribute__((ext_vector_type(4))) float f32x4;

__device__ __forceinline__ short f2bfs(float f) {
  unsigned x = __float_as_uint(f);
  unsigned r = x + 0x7fffu + ((x >> 16) & 1u);
  return (short)(r >> 16);
}
__device__ __forceinline__ unsigned short f2h(float f) {
  _Float16 h = (_Float16)f;
  return __builtin_bit_cast(unsigned short, h);
}
// pack two f32 -> two bf16 in one word (validated R2-R8)
__device__ __forceinline__ unsigned pk_bf16(float f0, float f1) {
  unsigned a0 = __float_as_uint(f0) + 0x8000u;
  unsigned a1 = __float_as_uint(f1) + 0x8000u;
  return __builtin_amdgcn_perm(a1, a0, 0x07060302u);
}
// branch-free tanh-form GELU (validated: absmax 0.0039 total)
__device__ __forceinline__ float geluf(float x) {
  float u = x * x;
  float p = __builtin_fmaf(u, 0.10294324f, 2.30220820f);
  float e = __builtin_amdgcn_exp2f(x * p);
  float r = __builtin_amdgcn_rcpf(e + 1.0f);
  return __builtin_fmaf(-x, r, x);
}
__device__ __forceinline__ float sigmoidf_(float x) {
  float e = __builtin_amdgcn_exp2f(x * -1.4426950408889634f);
  return __builtin_amdgcn_rcpf(1.0f + e);
}
// 16-lane DPP sum reduction on the VALU pipe (validated R5-R8)
template <int CTRL>
__device__ __forceinline__ float dpp_add(float x) {
  int v = __builtin_amdgcn_update_dpp(0, __float_as_int(x), CTRL, 0xf, 0xf, true);
  return x + __int_as_float(v);
}
__device__ __forceinline__ float red16(float x) {
  x = dpp_add<0xB1>(x);
  x = dpp_add<0x4E>(x);
  x = dpp_add<0x141>(x);
  x = dpp_add<0x140>(x);
  return x;
}

// ================= K_PRE: fused {uv+sums | repack | imp} ===================
// grid 816: [0,512) uv (2 rows/block), [512,560) repack, [560,816) imp
__global__ __launch_bounds__(256) void k_pre(
    const float* __restrict__ emb, const float* __restrict__ tf,
    const float* __restrict__ cW1, const float* __restrict__ cb1,
    const float* __restrict__ aW1, const float* __restrict__ ab1,
    const float* __restrict__ cW2, const float* __restrict__ aW2,
    const float* __restrict__ iW1, const float* __restrict__ ib1,
    const float* __restrict__ iW2, const float* __restrict__ ib2,
    float* __restrict__ ws, unsigned short* __restrict__ wsH,
    unsigned short* __restrict__ frag, float* __restrict__ out)
{
  __shared__ __align__(16) float sE[2][128];
  __shared__ float sRed[2][8];
  const int blk = blockIdx.x;
  const int t = threadIdx.x;
  const int lane = t & 63, wave = t >> 6;

  if (blk < 512) {
    const int b = blk;
    { int r = t >> 7, c = t & 127; sE[r][c] = emb[(b * 2 + r) * 128 + c]; }
    __syncthreads();
    const int k = t & 127;
    const bool cons = (t < 128);
    const float* W    = cons ? cW1 : aW1;
    const float* bias = cons ? cb1 : ab1;
    float accU0 = 0.f, accU1 = 0.f, accV0 = 0.f, accV1 = 0.f;
    for (int c = 0; c < 128; ++c) {
      float wt = W[c * 128 + k];
      float wb = W[(128 + c) * 128 + k];
      float e0 = sE[0][c], e1 = sE[1][c];
      accU0 = __builtin_fmaf(e0, wt, accU0);
      accU1 = __builtin_fmaf(e1, wt, accU1);
      accV0 = __builtin_fmaf(e0, wb, accV0);
      accV1 = __builtin_fmaf(e1, wb, accV1);
    }
    const float bv = bias[k];
    const float vb0 = accV0 + bv, vb1 = accV1 + bv;
    if (cons) {
      ws[WS_U + (b * 2 + 0) * 128 + k] = accU0;
      ws[WS_U + (b * 2 + 1) * 128 + k] = accU1;
      ws[WS_V + (b * 2 + 0) * 128 + k] = vb0;
      ws[WS_V + (b * 2 + 1) * 128 + k] = vb1;
      float vals[8] = {accU0, accU0 * accU0, accU1, accU1 * accU1,
                       vb0, vb0 * vb0, vb1, vb1 * vb1};
      #pragma unroll
      for (int msk = 1; msk <= 32; msk <<= 1)
        #pragma unroll
        for (int v = 0; v < 8; ++v) vals[v] += __shfl_xor(vals[v], msk, 64);
      if ((t & 63) == 0)
        #pragma unroll
        for (int v = 0; v < 8; ++v) sRed[t >> 6][v] = vals[v];
    } else {
      wsH[WS_UAH + (b * 2 + 0) * 128 + k] = f2h(accU0);
      wsH[WS_UAH + (b * 2 + 1) * 128 + k] = f2h(accU1);
      wsH[WS_VAH + (b * 2 + 0) * 128 + k] = f2h(vb0);
      wsH[WS_VAH + (b * 2 + 1) * 128 + k] = f2h(vb1);
    }
    __syncthreads();
    if (t == 0) {
      const int i0 = b * 2;
      ws[WS_SUMU + i0 * 2 + 0]       = sRed[0][0] + sRed[1][0];
      ws[WS_SUMU + i0 * 2 + 1]       = sRed[0][1] + sRed[1][1];
      ws[WS_SUMU + (i0 + 1) * 2 + 0] = sRed[0][2] + sRed[1][2];
      ws[WS_SUMU + (i0 + 1) * 2 + 1] = sRed[0][3] + sRed[1][3];
      ws[WS_SUMV + i0 * 2 + 0]       = sRed[0][4] + sRed[1][4];
      ws[WS_SUMV + i0 * 2 + 1]       = sRed[0][5] + sRed[1][5];
      ws[WS_SUMV + (i0 + 1) * 2 + 0] = sRed[0][6] + sRed[1][6];
      ws[WS_SUMV + (i0 + 1) * 2 + 1] = sRed[0][7] + sRed[1][7];
    }
  } else if (blk < 560) {
    int u = (blk - 512) * 256 + t;   // 0..12287
    if (u < 8192) {   // cons frags: bf16
      int j = u & 7, ln = (u >> 3) & 63, ks = (u >> 9) & 3, nt = u >> 11;
      frag[u] = (unsigned short)f2bfs(cW2[(ks * 32 + (ln >> 4) * 8 + j) * 64 + nt * 16 + (ln & 15)]);
    } else {          // assoc frags: f16
      int v = u - 8192;
      int j = v & 7, ln = (v >> 3) & 63, ks = (v >> 9) & 3, nt = v >> 11;
      frag[u] = f2h(aW2[(ks * 32 + (ln >> 4) * 8 + j) * 32 + nt * 16 + (ln & 15)]);
    }
  } else {
    const int r = (blk - 560) * 4 + wave;
    float acc = 0.f;
    for (int c = 0; c < 128; ++c)
      acc = __builtin_fmaf(emb[r * 128 + c], iW1[c * 64 + lane], acc);
    #pragma unroll
    for (int c = 0; c < 5; ++c)
      acc = __builtin_fmaf(tf[r * 5 + c], iW1[(128 + c) * 64 + lane], acc);
    float d = geluf(acc + ib1[lane]) * iW2[lane];
    #pragma unroll
    for (int msk = 32; msk; msk >>= 1) d += __shfl_xor(d, msk, 64);
    if (lane == 0) out[2 * P_PAIRS + r] = sigmoidf_(d + ib2[0]);
  }
}

// ================= K_PAIRS (static compact grid, LDS-light) ===============
// 1088 blocks enumerate valid (jt, i0) tiles; cum(jt) = 4jt(jt+1).
// LDS only 7.2 KB -> residency is wave-limited (8 blocks/CU capacity = 2048
// block slots >> 1088) => guaranteed single phase, zero tail.
// Weight frags are NOT staged in LDS: each MFMA's B-operand is a coalesced
// 1KB/instr global load (L1/L2-hot, shared across all blocks); the i-loop is
// kept rolled (#pragma unroll 1) so the 24 frag loads re-issue per iter
// instead of being hoisted into ~96 VGPRs.
// LN stats algebraic: mean=(su+sv)/128, E[x^2]=(qu+qv+2*dot)/128, dot fused.
__global__ __launch_bounds__(256, 8) void k_pairs(
    const float* __restrict__ ws, const unsigned short* __restrict__ wsH,
    const unsigned short* __restrict__ frag,
    const float* __restrict__ lng, const float* __restrict__ lnb,
    const float* __restrict__ cb2, const float* __restrict__ cW3,
    const float* __restrict__ cb3,
    const float* __restrict__ ab2, const float* __restrict__ aW3,
    const float* __restrict__ ab3,
    float* __restrict__ out)
{
  __shared__ __align__(16) float sU[TI][128];            // 4096 B
  __shared__ __align__(16) unsigned short sUaH[TI][128]; // 2048 B
  __shared__ __align__(16) float sG[128];                // 512 B
  __shared__ __align__(16) float sB[128];                // 512 B
  __shared__ float sSt[TI * 2];                          // 64 B => 7.2 KB
  const int t = threadIdx.x;

  // decode block -> (jt, i0); cum(jt) = 4jt(jt+1)
  const int b = blockIdx.x;
  int jt = (int)((sqrtf((float)b + 1.0f) - 1.0f) * 0.5f);
  while (4 * (jt + 1) * (jt + 2) <= b) ++jt;
  while (jt > 0 && 4 * jt * (jt + 1) > b) --jt;
  const int i0 = (b - 4 * jt * (jt + 1)) * TI;

  {
    int r = t >> 5, c4 = (t & 31) * 4;
    *(float4*)&sU[r][c4] = *(const float4*)(ws + WS_U + (i0 + r) * 128 + c4);
    *(ushort4*)&sUaH[r][c4] = *(const ushort4*)(wsH + WS_UAH + (i0 + r) * 128 + c4);
  }
  if (t < 128) { sG[t] = lng[t]; sB[t] = lnb[t]; }
  if (t < TI * 2) sSt[t] = ws[WS_SUMU + i0 * 2 + t];
  __syncthreads();

  const int lane = t & 63;
  const int wave = t >> 6;
  const int m = lane & 15;
  const int g = lane >> 4;
  const int j = jt * 64 + wave * 16 + m;
  const float* Vrow = ws + WS_V + j * 128;
  const float svj = ws[WS_SUMV + j * 2];
  const float qvj = ws[WS_SUMV + j * 2 + 1];

  // V row (cons, f32) and Va row (assoc, f16 packed) in registers
  float vC[4][8];
  h16x8 vAh[4];
  #pragma unroll
  for (int ks = 0; ks < 4; ++ks) {
    const int off = ks * 32 + g * 8;
    float4 a0 = *(const float4*)(Vrow + off);
    float4 a1 = *(const float4*)(Vrow + off + 4);
    vC[ks][0]=a0.x; vC[ks][1]=a0.y; vC[ks][2]=a0.z; vC[ks][3]=a0.w;
    vC[ks][4]=a1.x; vC[ks][5]=a1.y; vC[ks][6]=a1.z; vC[ks][7]=a1.w;
    vAh[ks] = *(const h16x8*)(wsH + WS_VAH + j * 128 + off);
  }

  float cb2v[4], cw3v[4], ab2v[2], aw3v[2];
  #pragma unroll
  for (int nt = 0; nt < 4; ++nt) { cb2v[nt] = cb2[nt * 16 + m]; cw3v[nt] = cW3[nt * 16 + m]; }
  #pragma unroll
  for (int nt = 0; nt < 2; ++nt) { ab2v[nt] = ab2[nt * 16 + m]; aw3v[nt] = aW3[nt * 16 + m]; }
  const float cb3s = cb3[0], ab3s = ab3[0];
  const bf16x8* bfr  = (const bf16x8*)frag;          // cons frags (global, hot)
  const h16x8*  bfrA = (const h16x8*)frag + 1024;    // assoc frags (global, hot)
  const f32x4 zero = {0.f, 0.f, 0.f, 0.f};
  const h16x8 hzero = {0, 0, 0, 0, 0, 0, 0, 0};
  const float inv128 = 0.0078125f;

  #pragma unroll 1
  for (int it = 0; it < TI; ++it) {
    const int i = i0 + it;
    if (jt * 64 + wave * 16 + 15 <= i) continue;   // wave-uniform skip

    const float* su_row = sU[it];

    // ---- pass 1: x = U+V (regs), fused dot = sum(U*V) ----
    float xc[4][8];
    float d = 0.f;
    #pragma unroll
    for (int ks = 0; ks < 4; ++ks) {
      const int off = ks * 32 + g * 8;
      float4 u0 = *(const float4*)(su_row + off);
      float4 u1 = *(const float4*)(su_row + off + 4);
      float us[8] = {u0.x,u0.y,u0.z,u0.w,u1.x,u1.y,u1.z,u1.w};
      #pragma unroll
      for (int s = 0; s < 8; ++s) {
        xc[ks][s] = us[s] + vC[ks][s];
        d = __builtin_fmaf(us[s], vC[ks][s], d);
      }
    }
    d += __shfl_xor(d, 16, 64);
    d += __shfl_xor(d, 32, 64);

    // ---- assoc phase 1 (f16 packed; overlaps shfl latency) ----
    h16x8 pA[4];
    #pragma unroll
    for (int ks = 0; ks < 4; ++ks) {
      const int off = ks * 32 + g * 8;
      h16x8 ua = *(const h16x8*)&sUaH[it][off];
      pA[ks] = __builtin_elementwise_max(ua + vAh[ks], hzero);
    }

    const float su = sSt[it * 2], qu = sSt[it * 2 + 1];
    const float mean = (su + svj) * inv128;
    const float ex2  = __builtin_fmaf(2.f, d, qu + qvj) * inv128;
    const float var  = ex2 - mean * mean;
    const float rstd = rsqrtf(var + 1e-5f);

    // ---- pass 2: gelu((x-mean)*rstd*G + B), pack bf16 ----
    int4 pC[4];
    #pragma unroll
    for (int ks = 0; ks < 4; ++ks) {
      const int off = ks * 32 + g * 8;
      float4 g0 = *(const float4*)(sG + off);
      float4 g1 = *(const float4*)(sG + off + 4);
      float4 b0 = *(const float4*)(sB + off);
      float4 b1 = *(const float4*)(sB + off + 4);
      float gg[8] = {g0.x,g0.y,g0.z,g0.w,g1.x,g1.y,g1.z,g1.w};
      float bb[8] = {b0.x,b0.y,b0.z,b0.w,b1.x,b1.y,b1.z,b1.w};
      float y[8];
      #pragma unroll
      for (int s = 0; s < 8; ++s) {
        float tq = (xc[ks][s] - mean) * rstd;
        y[s] = geluf(__builtin_fmaf(tq, gg[s], bb[s]));
      }
      pC[ks].x = pk_bf16(y[0], y[1]); pC[ks].y = pk_bf16(y[2], y[3]);
      pC[ks].z = pk_bf16(y[4], y[5]); pC[ks].w = pk_bf16(y[6], y[7]);
    }

    // ---- layer-2 GEMMs via MFMA (B-operands streamed from global) ----
    f32x4 accC[4] = {zero, zero, zero, zero};
    f32x4 accA[2] = {zero, zero};
    #pragma unroll
    for (int ks = 0; ks < 4; ++ks) {
      bf16x8 aC = __builtin_bit_cast(bf16x8, pC[ks]);
      #pragma unroll
      for (int nt = 0; nt < 4; ++nt)
        accC[nt] = __builtin_amdgcn_mfma_f32_16x16x32_bf16(
            aC, bfr[(nt * 4 + ks) * 64 + lane], accC[nt], 0, 0, 0);
      #pragma unroll
      for (int nt = 0; nt < 2; ++nt)
        accA[nt] = __builtin_amdgcn_mfma_f32_16x16x32_f16(
            pA[ks], bfrA[(nt * 4 + ks) * 64 + lane], accA[nt], 0, 0, 0);
    }

    // ---- layer 3: bias + act + dot W3; DPP 16-lane reduction ----
    float sc[4] = {0.f, 0.f, 0.f, 0.f};
    float sa[4] = {0.f, 0.f, 0.f, 0.f};
    #pragma unroll
    for (int nt = 0; nt < 4; ++nt)
      #pragma unroll
      for (int r = 0; r < 4; ++r)
        sc[r] = __builtin_fmaf(geluf(accC[nt][r] + cb2v[nt]), cw3v[nt], sc[r]);
    #pragma unroll
    for (int nt = 0; nt < 2; ++nt)
      #pragma unroll
      for (int r = 0; r < 4; ++r)
        sa[r] = __builtin_fmaf(fmaxf(accA[nt][r] + ab2v[nt], 0.f), aw3v[nt], sa[r]);
    #pragma unroll
    for (int r = 0; r < 4; ++r) { sc[r] = red16(sc[r]); sa[r] = red16(sa[r]); }

    if (m < 4) {
      const int jr = jt * 64 + wave * 16 + g * 4 + m;
      if (jr > i) {
        const int p = i * (2 * N_TR - i - 1) / 2 + (jr - i - 1);
        out[p]           = sigmoidf_(sc[m] + cb3s);
        out[P_PAIRS + p] = sigmoidf_(sa[m] + ab3s);
      }
    }
  }
}

extern "C" void kernel_launch(void* const* d_in, const int* in_sizes, int n_in,
                              void* d_out, int out_size, void* d_ws, size_t ws_size,
                              hipStream_t stream) {
  const float* emb = (const float*)d_in[0];
  const float* tf  = (const float*)d_in[1];
  const float* cW1 = (const float*)d_in[2];
  const float* cb1 = (const float*)d_in[3];
  const float* lng = (const float*)d_in[4];
  const float* lnb = (const float*)d_in[5];
  const float* cW2 = (const float*)d_in[6];
  const float* cb2 = (const float*)d_in[7];
  const float* cW3 = (const float*)d_in[8];
  const float* cb3 = (const float*)d_in[9];
  const float* aW1 = (const float*)d_in[10];
  const float* ab1 = (const float*)d_in[11];
  const float* aW2 = (const float*)d_in[12];
  const float* ab2 = (const float*)d_in[13];
  const float* aW3 = (const float*)d_in[14];
  const float* ab3 = (const float*)d_in[15];
  const float* iW1 = (const float*)d_in[16];
  const float* ib1 = (const float*)d_in[17];
  const float* iW2 = (const float*)d_in[18];
  const float* ib2 = (const float*)d_in[19];

  float* ws = (float*)d_ws;
  unsigned short* wsH = (unsigned short*)d_ws;
  unsigned short* frag = (unsigned short*)((char*)d_ws + WS_FRAG_BYTES);
  float* out = (float*)d_out;

  hipLaunchKernelGGL(k_pre, dim3(816), dim3(256), 0, stream,
                     emb, tf, cW1, cb1, aW1, ab1, cW2, aW2,
                     iW1, ib1, iW2, ib2, ws, wsH, frag, out);
  hipLaunchKernelGGL(k_pairs, dim3(N_BLOCKS), dim3(256), 0, stream,
                     ws, wsH, frag, lng, lnb, cb2, cW3, cb3, ab2, aW3, ab3, out);
}

// Round 10
// 172.816 us; speedup vs baseline: 1.9301x; 1.9301x over previous
//
#include <hip/hip_runtime.h>

#define N_TR 1024
#define H_DIM 128
#define P_PAIRS 523776   // N*(N-1)/2
#define TI 8             // i-rows per block tile
#define N_BLOCKS 1088    // sum over jt<16 of 8*(jt+1); cum(jt)=4jt(jt+1)
// ws float offsets (f32 regions)
#define WS_U    0
#define WS_V    131072
#define WS_SUMU 393216   // per i: {sumU, sumU2} (cons net)
#define WS_SUMV 395264   // per j: {sumV, sumV2} (cons net, V includes bias)
// ws ushort offsets (f16 regions)
#define WS_UAH  524288   // Ua as f16, 1024x128
#define WS_VAH  655360   // Va as f16 (incl bias), 1024x128
// ws byte offsets
#define WS_FRAG_BYTES 1589248u  // 12288 ushorts: [0,8192) cons bf16, [8192,12288) assoc f16

typedef __attribute__((ext_vector_type(8))) short bf16x8;
typedef __attribute__((ext_vector_type(8))) _Float16 h16x8;
typedef __attribute__((ext_vector_type(4))) float f32x4;

__device__ __forceinline__ short f2bfs(float f) {
  unsigned x = __float_as_uint(f);
  unsigned r = x + 0x7fffu + ((x >> 16) & 1u);
  return (short)(r >> 16);
}
__device__ __forceinline__ unsigned short f2h(float f) {
  _Float16 h = (_Float16)f;
  return __builtin_bit_cast(unsigned short, h);
}
// pack two f32 -> two bf16 in one word (validated R2-R8)
__device__ __forceinline__ unsigned pk_bf16(float f0, float f1) {
  unsigned a0 = __float_as_uint(f0) + 0x8000u;
  unsigned a1 = __float_as_uint(f1) + 0x8000u;
  return __builtin_amdgcn_perm(a1, a0, 0x07060302u);
}
// branch-free tanh-form GELU (validated: absmax 0.0039 total)
__device__ __forceinline__ float geluf(float x) {
  float u = x * x;
  float p = __builtin_fmaf(u, 0.10294324f, 2.30220820f);
  float e = __builtin_amdgcn_exp2f(x * p);
  float r = __builtin_amdgcn_rcpf(e + 1.0f);
  return __builtin_fmaf(-x, r, x);
}
__device__ __forceinline__ float sigmoidf_(float x) {
  float e = __builtin_amdgcn_exp2f(x * -1.4426950408889634f);
  return __builtin_amdgcn_rcpf(1.0f + e);
}
// 16-lane DPP sum reduction on the VALU pipe (validated R5-R8)
template <int CTRL>
__device__ __forceinline__ float dpp_add(float x) {
  int v = __builtin_amdgcn_update_dpp(0, __float_as_int(x), CTRL, 0xf, 0xf, true);
  return x + __int_as_float(v);
}
__device__ __forceinline__ float red16(float x) {
  x = dpp_add<0xB1>(x);
  x = dpp_add<0x4E>(x);
  x = dpp_add<0x141>(x);
  x = dpp_add<0x140>(x);
  return x;
}

// ================= K_PRE: fused {uv+sums | repack | imp} ===================
// grid 816: [0,512) uv (2 rows/block), [512,560) repack, [560,816) imp
__global__ __launch_bounds__(256) void k_pre(
    const float* __restrict__ emb, const float* __restrict__ tf,
    const float* __restrict__ cW1, const float* __restrict__ cb1,
    const float* __restrict__ aW1, const float* __restrict__ ab1,
    const float* __restrict__ cW2, const float* __restrict__ aW2,
    const float* __restrict__ iW1, const float* __restrict__ ib1,
    const float* __restrict__ iW2, const float* __restrict__ ib2,
    float* __restrict__ ws, unsigned short* __restrict__ wsH,
    unsigned short* __restrict__ frag, float* __restrict__ out)
{
  __shared__ __align__(16) float sE[2][128];
  __shared__ float sRed[2][8];
  const int blk = blockIdx.x;
  const int t = threadIdx.x;
  const int lane = t & 63, wave = t >> 6;

  if (blk < 512) {
    const int b = blk;
    { int r = t >> 7, c = t & 127; sE[r][c] = emb[(b * 2 + r) * 128 + c]; }
    __syncthreads();
    const int k = t & 127;
    const bool cons = (t < 128);
    const float* W    = cons ? cW1 : aW1;
    const float* bias = cons ? cb1 : ab1;
    float accU0 = 0.f, accU1 = 0.f, accV0 = 0.f, accV1 = 0.f;
    for (int c = 0; c < 128; ++c) {
      float wt = W[c * 128 + k];
      float wb = W[(128 + c) * 128 + k];
      float e0 = sE[0][c], e1 = sE[1][c];
      accU0 = __builtin_fmaf(e0, wt, accU0);
      accU1 = __builtin_fmaf(e1, wt, accU1);
      accV0 = __builtin_fmaf(e0, wb, accV0);
      accV1 = __builtin_fmaf(e1, wb, accV1);
    }
    const float bv = bias[k];
    const float vb0 = accV0 + bv, vb1 = accV1 + bv;
    if (cons) {
      ws[WS_U + (b * 2 + 0) * 128 + k] = accU0;
      ws[WS_U + (b * 2 + 1) * 128 + k] = accU1;
      ws[WS_V + (b * 2 + 0) * 128 + k] = vb0;
      ws[WS_V + (b * 2 + 1) * 128 + k] = vb1;
      float vals[8] = {accU0, accU0 * accU0, accU1, accU1 * accU1,
                       vb0, vb0 * vb0, vb1, vb1 * vb1};
      #pragma unroll
      for (int msk = 1; msk <= 32; msk <<= 1)
        #pragma unroll
        for (int v = 0; v < 8; ++v) vals[v] += __shfl_xor(vals[v], msk, 64);
      if ((t & 63) == 0)
        #pragma unroll
        for (int v = 0; v < 8; ++v) sRed[t >> 6][v] = vals[v];
    } else {
      wsH[WS_UAH + (b * 2 + 0) * 128 + k] = f2h(accU0);
      wsH[WS_UAH + (b * 2 + 1) * 128 + k] = f2h(accU1);
      wsH[WS_VAH + (b * 2 + 0) * 128 + k] = f2h(vb0);
      wsH[WS_VAH + (b * 2 + 1) * 128 + k] = f2h(vb1);
    }
    __syncthreads();
    if (t == 0) {
      const int i0 = b * 2;
      ws[WS_SUMU + i0 * 2 + 0]       = sRed[0][0] + sRed[1][0];
      ws[WS_SUMU + i0 * 2 + 1]       = sRed[0][1] + sRed[1][1];
      ws[WS_SUMU + (i0 + 1) * 2 + 0] = sRed[0][2] + sRed[1][2];
      ws[WS_SUMU + (i0 + 1) * 2 + 1] = sRed[0][3] + sRed[1][3];
      ws[WS_SUMV + i0 * 2 + 0]       = sRed[0][4] + sRed[1][4];
      ws[WS_SUMV + i0 * 2 + 1]       = sRed[0][5] + sRed[1][5];
      ws[WS_SUMV + (i0 + 1) * 2 + 0] = sRed[0][6] + sRed[1][6];
      ws[WS_SUMV + (i0 + 1) * 2 + 1] = sRed[0][7] + sRed[1][7];
    }
  } else if (blk < 560) {
    int u = (blk - 512) * 256 + t;   // 0..12287
    if (u < 8192) {   // cons frags: bf16
      int j = u & 7, ln = (u >> 3) & 63, ks = (u >> 9) & 3, nt = u >> 11;
      frag[u] = (unsigned short)f2bfs(cW2[(ks * 32 + (ln >> 4) * 8 + j) * 64 + nt * 16 + (ln & 15)]);
    } else {          // assoc frags: f16
      int v = u - 8192;
      int j = v & 7, ln = (v >> 3) & 63, ks = (v >> 9) & 3, nt = v >> 11;
      frag[u] = f2h(aW2[(ks * 32 + (ln >> 4) * 8 + j) * 32 + nt * 16 + (ln & 15)]);
    }
  } else {
    const int r = (blk - 560) * 4 + wave;
    float acc = 0.f;
    for (int c = 0; c < 128; ++c)
      acc = __builtin_fmaf(emb[r * 128 + c], iW1[c * 64 + lane], acc);
    #pragma unroll
    for (int c = 0; c < 5; ++c)
      acc = __builtin_fmaf(tf[r * 5 + c], iW1[(128 + c) * 64 + lane], acc);
    float d = geluf(acc + ib1[lane]) * iW2[lane];
    #pragma unroll
    for (int msk = 32; msk; msk >>= 1) d += __shfl_xor(d, msk, 64);
    if (lane == 0) out[2 * P_PAIRS + r] = sigmoidf_(d + ib2[0]);
  }
}

// ================= K_PAIRS (static compact grid; NO SPILLS) ===============
// 1088 blocks enumerate valid (jt, i0) tiles; cum(jt) = 4jt(jt+1).
// __launch_bounds__(256,4): VGPR cap 128 — the live set (vC 32 + xc 32 +
// accs + frags) needs ~110; capping at 5 waves (102) caused hidden scratch
// spills (R8: FETCH 122MB, R9 catastrophically). 4 blocks/CU, 64-block tail
// accepted — spills cost more than the tail (R5 evidence).
// Wave w owns j = jt*64+w*16+(lane&15); lane k-slice ks*32+(lane>>4)*8+s.
// LN stats algebraic: mean=(su+sv)/128, E[x^2]=(qu+qv+2*dot)/128, dot fused
// into the U+V pass. Assoc net f16-packed end-to-end.
__global__ __launch_bounds__(256, 4) void k_pairs(
    const float* __restrict__ ws, const unsigned short* __restrict__ wsH,
    const unsigned short* __restrict__ frag,
    const float* __restrict__ lng, const float* __restrict__ lnb,
    const float* __restrict__ cb2, const float* __restrict__ cW3,
    const float* __restrict__ cb3,
    const float* __restrict__ ab2, const float* __restrict__ aW3,
    const float* __restrict__ ab3,
    float* __restrict__ out)
{
  __shared__ __align__(16) unsigned short sFrag[12288];  // 24576 B
  __shared__ __align__(16) float sU[TI][128];            // 4096 B
  __shared__ __align__(16) unsigned short sUaH[TI][128]; // 2048 B
  __shared__ __align__(16) float sG[128];                // 512 B
  __shared__ __align__(16) float sB[128];                // 512 B
  __shared__ float sSt[TI * 2];                          // 64 B => 31.8 KB
  const int t = threadIdx.x;

  // decode block -> (jt, i0); cum(jt) = 4jt(jt+1)
  const int b = blockIdx.x;
  int jt = (int)((sqrtf((float)b + 1.0f) - 1.0f) * 0.5f);
  while (4 * (jt + 1) * (jt + 2) <= b) ++jt;
  while (jt > 0 && 4 * jt * (jt + 1) > b) --jt;
  const int i0 = (b - 4 * jt * (jt + 1)) * TI;

  {
    const uint4* src = (const uint4*)frag;
    uint4* dst = (uint4*)sFrag;
    #pragma unroll
    for (int q = 0; q < 6; ++q) dst[t + q * 256] = src[t + q * 256];
  }
  {
    int r = t >> 5, c4 = (t & 31) * 4;
    *(float4*)&sU[r][c4] = *(const float4*)(ws + WS_U + (i0 + r) * 128 + c4);
    *(ushort4*)&sUaH[r][c4] = *(const ushort4*)(wsH + WS_UAH + (i0 + r) * 128 + c4);
  }
  if (t < 128) { sG[t] = lng[t]; sB[t] = lnb[t]; }
  if (t < TI * 2) sSt[t] = ws[WS_SUMU + i0 * 2 + t];
  __syncthreads();

  const int lane = t & 63;
  const int wave = t >> 6;
  const int m = lane & 15;
  const int g = lane >> 4;
  const int j = jt * 64 + wave * 16 + m;
  const float* Vrow = ws + WS_V + j * 128;
  const float svj = ws[WS_SUMV + j * 2];
  const float qvj = ws[WS_SUMV + j * 2 + 1];

  // V row (cons, f32) and Va row (assoc, f16 packed) in registers
  float vC[4][8];
  h16x8 vAh[4];
  #pragma unroll
  for (int ks = 0; ks < 4; ++ks) {
    const int off = ks * 32 + g * 8;
    float4 a0 = *(const float4*)(Vrow + off);
    float4 a1 = *(const float4*)(Vrow + off + 4);
    vC[ks][0]=a0.x; vC[ks][1]=a0.y; vC[ks][2]=a0.z; vC[ks][3]=a0.w;
    vC[ks][4]=a1.x; vC[ks][5]=a1.y; vC[ks][6]=a1.z; vC[ks][7]=a1.w;
    vAh[ks] = *(const h16x8*)(wsH + WS_VAH + j * 128 + off);
  }

  float cb2v[4], cw3v[4], ab2v[2], aw3v[2];
  #pragma unroll
  for (int nt = 0; nt < 4; ++nt) { cb2v[nt] = cb2[nt * 16 + m]; cw3v[nt] = cW3[nt * 16 + m]; }
  #pragma unroll
  for (int nt = 0; nt < 2; ++nt) { ab2v[nt] = ab2[nt * 16 + m]; aw3v[nt] = aW3[nt * 16 + m]; }
  const float cb3s = cb3[0], ab3s = ab3[0];
  const bf16x8* bfr  = (const bf16x8*)sFrag;          // cons frags [0,1024)
  const h16x8*  bfrA = (const h16x8*)sFrag + 1024;    // assoc frags
  const f32x4 zero = {0.f, 0.f, 0.f, 0.f};
  const h16x8 hzero = {0, 0, 0, 0, 0, 0, 0, 0};
  const float inv128 = 0.0078125f;

  for (int it = 0; it < TI; ++it) {
    const int i = i0 + it;
    if (jt * 64 + wave * 16 + 15 <= i) continue;   // wave-uniform skip

    const float* su_row = sU[it];

    // ---- pass 1: x = U+V (regs), fused dot = sum(U*V) ----
    float xc[4][8];
    float d = 0.f;
    #pragma unroll
    for (int ks = 0; ks < 4; ++ks) {
      const int off = ks * 32 + g * 8;
      float4 u0 = *(const float4*)(su_row + off);
      float4 u1 = *(const float4*)(su_row + off + 4);
      float us[8] = {u0.x,u0.y,u0.z,u0.w,u1.x,u1.y,u1.z,u1.w};
      #pragma unroll
      for (int s = 0; s < 8; ++s) {
        xc[ks][s] = us[s] + vC[ks][s];
        d = __builtin_fmaf(us[s], vC[ks][s], d);
      }
    }
    d += __shfl_xor(d, 16, 64);
    d += __shfl_xor(d, 32, 64);

    // ---- assoc phase 1 (f16 packed; overlaps shfl latency) ----
    h16x8 pA[4];
    #pragma unroll
    for (int ks = 0; ks < 4; ++ks) {
      const int off = ks * 32 + g * 8;
      h16x8 ua = *(const h16x8*)&sUaH[it][off];
      pA[ks] = __builtin_elementwise_max(ua + vAh[ks], hzero);
    }

    const float su = sSt[it * 2], qu = sSt[it * 2 + 1];
    const float mean = (su + svj) * inv128;
    const float ex2  = __builtin_fmaf(2.f, d, qu + qvj) * inv128;
    const float var  = ex2 - mean * mean;
    const float rstd = rsqrtf(var + 1e-5f);

    // ---- pass 2: gelu((x-mean)*rstd*G + B), pack bf16 ----
    int4 pC[4];
    #pragma unroll
    for (int ks = 0; ks < 4; ++ks) {
      const int off = ks * 32 + g * 8;
      float4 g0 = *(const float4*)(sG + off);
      float4 g1 = *(const float4*)(sG + off + 4);
      float4 b0 = *(const float4*)(sB + off);
      float4 b1 = *(const float4*)(sB + off + 4);
      float gg[8] = {g0.x,g0.y,g0.z,g0.w,g1.x,g1.y,g1.z,g1.w};
      float bb[8] = {b0.x,b0.y,b0.z,b0.w,b1.x,b1.y,b1.z,b1.w};
      float y[8];
      #pragma unroll
      for (int s = 0; s < 8; ++s) {
        float tq = (xc[ks][s] - mean) * rstd;
        y[s] = geluf(__builtin_fmaf(tq, gg[s], bb[s]));
      }
      pC[ks].x = pk_bf16(y[0], y[1]); pC[ks].y = pk_bf16(y[2], y[3]);
      pC[ks].z = pk_bf16(y[4], y[5]); pC[ks].w = pk_bf16(y[6], y[7]);
    }

    // ---- layer-2 GEMMs via MFMA (cons bf16, assoc f16) ----
    f32x4 accC[4] = {zero, zero, zero, zero};
    f32x4 accA[2] = {zero, zero};
    #pragma unroll
    for (int ks = 0; ks < 4; ++ks) {
      bf16x8 aC = __builtin_bit_cast(bf16x8, pC[ks]);
      #pragma unroll
      for (int nt = 0; nt < 4; ++nt)
        accC[nt] = __builtin_amdgcn_mfma_f32_16x16x32_bf16(
            aC, bfr[(nt * 4 + ks) * 64 + lane], accC[nt], 0, 0, 0);
      #pragma unroll
      for (int nt = 0; nt < 2; ++nt)
        accA[nt] = __builtin_amdgcn_mfma_f32_16x16x32_f16(
            pA[ks], bfrA[(nt * 4 + ks) * 64 + lane], accA[nt], 0, 0, 0);
    }

    // ---- layer 3: bias + act + dot W3; DPP 16-lane reduction ----
    float sc[4] = {0.f, 0.f, 0.f, 0.f};
    float sa[4] = {0.f, 0.f, 0.f, 0.f};
    #pragma unroll
    for (int nt = 0; nt < 4; ++nt)
      #pragma unroll
      for (int r = 0; r < 4; ++r)
        sc[r] = __builtin_fmaf(geluf(accC[nt][r] + cb2v[nt]), cw3v[nt], sc[r]);
    #pragma unroll
    for (int nt = 0; nt < 2; ++nt)
      #pragma unroll
      for (int r = 0; r < 4; ++r)
        sa[r] = __builtin_fmaf(fmaxf(accA[nt][r] + ab2v[nt], 0.f), aw3v[nt], sa[r]);
    #pragma unroll
    for (int r = 0; r < 4; ++r) { sc[r] = red16(sc[r]); sa[r] = red16(sa[r]); }

    if (m < 4) {
      const int jr = jt * 64 + wave * 16 + g * 4 + m;
      if (jr > i) {
        const int p = i * (2 * N_TR - i - 1) / 2 + (jr - i - 1);
        out[p]           = sigmoidf_(sc[m] + cb3s);
        out[P_PAIRS + p] = sigmoidf_(sa[m] + ab3s);
      }
    }
  }
}

extern "C" void kernel_launch(void* const* d_in, const int* in_sizes, int n_in,
                              void* d_out, int out_size, void* d_ws, size_t ws_size,
                              hipStream_t stream) {
  const float* emb = (const float*)d_in[0];
  const float* tf  = (const float*)d_in[1];
  const float* cW1 = (const float*)d_in[2];
  const float* cb1 = (const float*)d_in[3];
  const float* lng = (const float*)d_in[4];
  const float* lnb = (const float*)d_in[5];
  const float* cW2 = (const float*)d_in[6];
  const float* cb2 = (const float*)d_in[7];
  const float* cW3 = (const float*)d_in[8];
  const float* cb3 = (const float*)d_in[9];
  const float* aW1 = (const float*)d_in[10];
  const float* ab1 = (const float*)d_in[11];
  const float* aW2 = (const float*)d_in[12];
  const float* ab2 = (const float*)d_in[13];
  const float* aW3 = (const float*)d_in[14];
  const float* ab3 = (const float*)d_in[15];
  const float* iW1 = (const float*)d_in[16];
  const float* ib1 = (const float*)d_in[17];
  const float* iW2 = (const float*)d_in[18];
  const float* ib2 = (const float*)d_in[19];

  float* ws = (float*)d_ws;
  unsigned short* wsH = (unsigned short*)d_ws;
  unsigned short* frag = (unsigned short*)((char*)d_ws + WS_FRAG_BYTES);
  float* out = (float*)d_out;

  hipLaunchKernelGGL(k_pre, dim3(816), dim3(256), 0, stream,
                     emb, tf, cW1, cb1, aW1, ab1, cW2, aW2,
                     iW1, ib1, iW2, ib2, ws, wsH, frag, out);
  hipLaunchKernelGGL(k_pairs, dim3(N_BLOCKS), dim3(256), 0, stream,
                     ws, wsH, frag, lng, lnb, cb2, cW3, cb3, ab2, aW3, ab3, out);
}

// Round 11
// 167.376 us; speedup vs baseline: 1.9928x; 1.0325x over previous
//
#include <hip/hip_runtime.h>

#define N_TR 1024
#define H_DIM 128
#define P_PAIRS 523776   // N*(N-1)/2
#define N_UNITS 8688     // sum over jt<16 of (64*jt+63); C(jt)=32jt^2+31jt
#define MAX_SLOTS 9
// ws float offsets (f32 regions)
#define WS_U    0
#define WS_V    131072
#define WS_SUMU 393216   // per i: {sumU, sumU2} (cons net)
#define WS_SUMV 395264   // per j: {sumV, sumV2} (cons net, V includes bias)
// ws ushort offsets (f16 regions)
#define WS_UAH  524288   // Ua as f16, 1024x128
#define WS_VAH  655360   // Va as f16 (incl bias), 1024x128
// ws byte offsets
#define WS_FRAG_BYTES 1589248u  // 12288 ushorts: [0,8192) cons bf16, [8192,12288) assoc f16

typedef __attribute__((ext_vector_type(8))) short bf16x8;
typedef __attribute__((ext_vector_type(8))) _Float16 h16x8;
typedef __attribute__((ext_vector_type(4))) float f32x4;

__device__ __forceinline__ short f2bfs(float f) {
  unsigned x = __float_as_uint(f);
  unsigned r = x + 0x7fffu + ((x >> 16) & 1u);
  return (short)(r >> 16);
}
__device__ __forceinline__ unsigned short f2h(float f) {
  _Float16 h = (_Float16)f;
  return __builtin_bit_cast(unsigned short, h);
}
// pack two f32 -> two bf16 in one word (validated R2-R10)
__device__ __forceinline__ unsigned pk_bf16(float f0, float f1) {
  unsigned a0 = __float_as_uint(f0) + 0x8000u;
  unsigned a1 = __float_as_uint(f1) + 0x8000u;
  return __builtin_amdgcn_perm(a1, a0, 0x07060302u);
}
// branch-free tanh-form GELU (validated: absmax 0.0039 total)
__device__ __forceinline__ float geluf(float x) {
  float u = x * x;
  float p = __builtin_fmaf(u, 0.10294324f, 2.30220820f);
  float e = __builtin_amdgcn_exp2f(x * p);
  float r = __builtin_amdgcn_rcpf(e + 1.0f);
  return __builtin_fmaf(-x, r, x);
}
__device__ __forceinline__ float sigmoidf_(float x) {
  float e = __builtin_amdgcn_exp2f(x * -1.4426950408889634f);
  return __builtin_amdgcn_rcpf(1.0f + e);
}
// 16-lane DPP sum reduction on the VALU pipe (validated R5-R10)
template <int CTRL>
__device__ __forceinline__ float dpp_add(float x) {
  int v = __builtin_amdgcn_update_dpp(0, __float_as_int(x), CTRL, 0xf, 0xf, true);
  return x + __int_as_float(v);
}
__device__ __forceinline__ float red16(float x) {
  x = dpp_add<0xB1>(x);
  x = dpp_add<0x4E>(x);
  x = dpp_add<0x141>(x);
  x = dpp_add<0x140>(x);
  return x;
}
// decode unit -> jt; C(jt) = 32jt^2 + 31jt
__device__ __forceinline__ int jt_from_u(int u) {
  float f = (sqrtf(961.0f + 128.0f * (float)u) - 31.0f) * 0.015625f;
  int jt = (int)f;
  if (jt > 15) jt = 15;
  while (jt < 15 && 32 * (jt + 1) * (jt + 1) + 31 * (jt + 1) <= u) ++jt;
  while (jt > 0 && 32 * jt * jt + 31 * jt > u) --jt;
  return jt;
}

// ================= K_PRE: fused {uv+sums | repack | imp} ===================
// grid 816: [0,512) uv (2 rows/block), [512,560) repack, [560,816) imp
__global__ __launch_bounds__(256) void k_pre(
    const float* __restrict__ emb, const float* __restrict__ tf,
    const float* __restrict__ cW1, const float* __restrict__ cb1,
    const float* __restrict__ aW1, const float* __restrict__ ab1,
    const float* __restrict__ cW2, const float* __restrict__ aW2,
    const float* __restrict__ iW1, const float* __restrict__ ib1,
    const float* __restrict__ iW2, const float* __restrict__ ib2,
    float* __restrict__ ws, unsigned short* __restrict__ wsH,
    unsigned short* __restrict__ frag, float* __restrict__ out)
{
  __shared__ __align__(16) float sE[2][128];
  __shared__ float sRed[2][8];
  const int blk = blockIdx.x;
  const int t = threadIdx.x;
  const int lane = t & 63, wave = t >> 6;

  if (blk < 512) {
    const int b = blk;
    { int r = t >> 7, c = t & 127; sE[r][c] = emb[(b * 2 + r) * 128 + c]; }
    __syncthreads();
    const int k = t & 127;
    const bool cons = (t < 128);
    const float* W    = cons ? cW1 : aW1;
    const float* bias = cons ? cb1 : ab1;
    float accU0 = 0.f, accU1 = 0.f, accV0 = 0.f, accV1 = 0.f;
    for (int c = 0; c < 128; ++c) {
      float wt = W[c * 128 + k];
      float wb = W[(128 + c) * 128 + k];
      float e0 = sE[0][c], e1 = sE[1][c];
      accU0 = __builtin_fmaf(e0, wt, accU0);
      accU1 = __builtin_fmaf(e1, wt, accU1);
      accV0 = __builtin_fmaf(e0, wb, accV0);
      accV1 = __builtin_fmaf(e1, wb, accV1);
    }
    const float bv = bias[k];
    const float vb0 = accV0 + bv, vb1 = accV1 + bv;
    if (cons) {
      ws[WS_U + (b * 2 + 0) * 128 + k] = accU0;
      ws[WS_U + (b * 2 + 1) * 128 + k] = accU1;
      ws[WS_V + (b * 2 + 0) * 128 + k] = vb0;
      ws[WS_V + (b * 2 + 1) * 128 + k] = vb1;
      float vals[8] = {accU0, accU0 * accU0, accU1, accU1 * accU1,
                       vb0, vb0 * vb0, vb1, vb1 * vb1};
      #pragma unroll
      for (int msk = 1; msk <= 32; msk <<= 1)
        #pragma unroll
        for (int v = 0; v < 8; ++v) vals[v] += __shfl_xor(vals[v], msk, 64);
      if ((t & 63) == 0)
        #pragma unroll
        for (int v = 0; v < 8; ++v) sRed[t >> 6][v] = vals[v];
    } else {
      wsH[WS_UAH + (b * 2 + 0) * 128 + k] = f2h(accU0);
      wsH[WS_UAH + (b * 2 + 1) * 128 + k] = f2h(accU1);
      wsH[WS_VAH + (b * 2 + 0) * 128 + k] = f2h(vb0);
      wsH[WS_VAH + (b * 2 + 1) * 128 + k] = f2h(vb1);
    }
    __syncthreads();
    if (t == 0) {
      const int i0 = b * 2;
      ws[WS_SUMU + i0 * 2 + 0]       = sRed[0][0] + sRed[1][0];
      ws[WS_SUMU + i0 * 2 + 1]       = sRed[0][1] + sRed[1][1];
      ws[WS_SUMU + (i0 + 1) * 2 + 0] = sRed[0][2] + sRed[1][2];
      ws[WS_SUMU + (i0 + 1) * 2 + 1] = sRed[0][3] + sRed[1][3];
      ws[WS_SUMV + i0 * 2 + 0]       = sRed[0][4] + sRed[1][4];
      ws[WS_SUMV + i0 * 2 + 1]       = sRed[0][5] + sRed[1][5];
      ws[WS_SUMV + (i0 + 1) * 2 + 0] = sRed[0][6] + sRed[1][6];
      ws[WS_SUMV + (i0 + 1) * 2 + 1] = sRed[0][7] + sRed[1][7];
    }
  } else if (blk < 560) {
    int u = (blk - 512) * 256 + t;   // 0..12287
    if (u < 8192) {   // cons frags: bf16
      int j = u & 7, ln = (u >> 3) & 63, ks = (u >> 9) & 3, nt = u >> 11;
      frag[u] = (unsigned short)f2bfs(cW2[(ks * 32 + (ln >> 4) * 8 + j) * 64 + nt * 16 + (ln & 15)]);
    } else {          // assoc frags: f16
      int v = u - 8192;
      int j = v & 7, ln = (v >> 3) & 63, ks = (v >> 9) & 3, nt = v >> 11;
      frag[u] = f2h(aW2[(ks * 32 + (ln >> 4) * 8 + j) * 32 + nt * 16 + (ln & 15)]);
    }
  } else {
    const int r = (blk - 560) * 4 + wave;
    float acc = 0.f;
    for (int c = 0; c < 128; ++c)
      acc = __builtin_fmaf(emb[r * 128 + c], iW1[c * 64 + lane], acc);
    #pragma unroll
    for (int c = 0; c < 5; ++c)
      acc = __builtin_fmaf(tf[r * 5 + c], iW1[(128 + c) * 64 + lane], acc);
    float d = geluf(acc + ib1[lane]) * iW2[lane];
    #pragma unroll
    for (int msk = 32; msk; msk >>= 1) d += __shfl_xor(d, msk, 64);
    if (lane == 0) out[2 * P_PAIRS + r] = sigmoidf_(d + ib2[0]);
  }
}

// ================= K_PAIRS (balanced static grid, fine units) =============
// 8688 units (jt, i) over 1024 blocks: block b takes units [543b>>6,
// 543(b+1)>>6) = 8-9 units -> zero tail (makespan 9 vs prior 16 iter-times),
// no atomics, one barrier. Block stages its <=9 U/Ua rows + unit meta in LDS;
// V/Va register-cached, reloaded only on (rare, block-uniform) jt change.
// __launch_bounds__(256,4): VGPR cap 128 — caps below this spill/demote vC
// (R8/R9 post-mortems). 4 blocks/CU, LDS 32.7 KB.
__global__ __launch_bounds__(256, 4) void k_pairs(
    const float* __restrict__ ws, const unsigned short* __restrict__ wsH,
    const unsigned short* __restrict__ frag,
    const float* __restrict__ lng, const float* __restrict__ lnb,
    const float* __restrict__ cb2, const float* __restrict__ cW3,
    const float* __restrict__ cb3,
    const float* __restrict__ ab2, const float* __restrict__ aW3,
    const float* __restrict__ ab3,
    float* __restrict__ out)
{
  __shared__ __align__(16) unsigned short sFrag[12288];      // 24576 B
  __shared__ __align__(16) float sU[MAX_SLOTS][128];         // 4608 B
  __shared__ __align__(16) unsigned short sUaH[MAX_SLOTS][128]; // 2304 B
  __shared__ __align__(16) float sG[128];                    // 512 B
  __shared__ __align__(16) float sB[128];                    // 512 B
  __shared__ float sSt[MAX_SLOTS * 2];                       // 72 B
  __shared__ int sJt[MAX_SLOTS], sI[MAX_SLOTS];              // 72 B
  const int t = threadIdx.x;
  const int b = blockIdx.x;
  const int u0 = (543 * b) >> 6;
  const int u1 = (543 * (b + 1)) >> 6;
  const int n  = u1 - u0;          // 8 or 9

  {
    const uint4* src = (const uint4*)frag;
    uint4* dst = (uint4*)sFrag;
    #pragma unroll
    for (int q = 0; q < 6; ++q) dst[t + q * 256] = src[t + q * 256];
  }
  if (t < n) {
    int u = u0 + t;
    int jtu = jt_from_u(u);
    sJt[t] = jtu;
    sI[t]  = u - (32 * jtu * jtu + 31 * jtu);
  }
  for (int s = t >> 5; s < n; s += 8) {
    int u = u0 + s;
    int jtu = jt_from_u(u);
    int iu = u - (32 * jtu * jtu + 31 * jtu);
    int c4 = (t & 31) * 4;
    *(float4*)&sU[s][c4] = *(const float4*)(ws + WS_U + iu * 128 + c4);
    *(ushort4*)&sUaH[s][c4] = *(const ushort4*)(wsH + WS_UAH + iu * 128 + c4);
  }
  if (t < 2 * n) {
    int s = t >> 1;
    int u = u0 + s;
    int jtu = jt_from_u(u);
    int iu = u - (32 * jtu * jtu + 31 * jtu);
    sSt[t] = ws[WS_SUMU + iu * 2 + (t & 1)];
  }
  if (t < 128) { sG[t] = lng[t]; sB[t] = lnb[t]; }
  __syncthreads();

  const int lane = t & 63;
  const int wave = t >> 6;
  const int m = lane & 15;
  const int g = lane >> 4;

  float cb2v[4], cw3v[4], ab2v[2], aw3v[2];
  #pragma unroll
  for (int nt = 0; nt < 4; ++nt) { cb2v[nt] = cb2[nt * 16 + m]; cw3v[nt] = cW3[nt * 16 + m]; }
  #pragma unroll
  for (int nt = 0; nt < 2; ++nt) { ab2v[nt] = ab2[nt * 16 + m]; aw3v[nt] = aW3[nt * 16 + m]; }
  const float cb3s = cb3[0], ab3s = ab3[0];
  const bf16x8* bfr  = (const bf16x8*)sFrag;          // cons frags [0,1024)
  const h16x8*  bfrA = (const h16x8*)sFrag + 1024;    // assoc frags
  const f32x4 zero = {0.f, 0.f, 0.f, 0.f};
  const h16x8 hzero = {0, 0, 0, 0, 0, 0, 0, 0};
  const float inv128 = 0.0078125f;

  int jt_cur = -1;
  float svj = 0.f, qvj = 0.f;
  float vC[4][8];
  h16x8 vAh[4];

  for (int s = 0; s < n; ++s) {
    const int jtu = sJt[s];
    const int i   = sI[s];
    if (jtu != jt_cur) {            // block-uniform; <=2 times per block
      jt_cur = jtu;
      const int j = jtu * 64 + wave * 16 + m;
      const float* Vrow = ws + WS_V + j * 128;
      #pragma unroll
      for (int ks = 0; ks < 4; ++ks) {
        const int off = ks * 32 + g * 8;
        float4 a0 = *(const float4*)(Vrow + off);
        float4 a1 = *(const float4*)(Vrow + off + 4);
        vC[ks][0]=a0.x; vC[ks][1]=a0.y; vC[ks][2]=a0.z; vC[ks][3]=a0.w;
        vC[ks][4]=a1.x; vC[ks][5]=a1.y; vC[ks][6]=a1.z; vC[ks][7]=a1.w;
        vAh[ks] = *(const h16x8*)(wsH + WS_VAH + j * 128 + off);
      }
      svj = ws[WS_SUMV + j * 2];
      qvj = ws[WS_SUMV + j * 2 + 1];
    }
    if (jt_cur * 64 + wave * 16 + 15 <= i) continue;   // wave-uniform skip

    const float* su_row = sU[s];

    // ---- pass 1: x = U+V (regs), fused dot = sum(U*V) ----
    float xc[4][8];
    float d = 0.f;
    #pragma unroll
    for (int ks = 0; ks < 4; ++ks) {
      const int off = ks * 32 + g * 8;
      float4 u0v = *(const float4*)(su_row + off);
      float4 u1v = *(const float4*)(su_row + off + 4);
      float us[8] = {u0v.x,u0v.y,u0v.z,u0v.w,u1v.x,u1v.y,u1v.z,u1v.w};
      #pragma unroll
      for (int q = 0; q < 8; ++q) {
        xc[ks][q] = us[q] + vC[ks][q];
        d = __builtin_fmaf(us[q], vC[ks][q], d);
      }
    }
    d += __shfl_xor(d, 16, 64);
    d += __shfl_xor(d, 32, 64);

    // ---- assoc phase 1 (f16 packed; overlaps shfl latency) ----
    h16x8 pA[4];
    #pragma unroll
    for (int ks = 0; ks < 4; ++ks) {
      const int off = ks * 32 + g * 8;
      h16x8 ua = *(const h16x8*)&sUaH[s][off];
      pA[ks] = __builtin_elementwise_max(ua + vAh[ks], hzero);
    }

    const float su = sSt[s * 2], qu = sSt[s * 2 + 1];
    const float mean = (su + svj) * inv128;
    const float ex2  = __builtin_fmaf(2.f, d, qu + qvj) * inv128;
    const float var  = ex2 - mean * mean;
    const float rstd = rsqrtf(var + 1e-5f);
    const float nms  = -mean * rstd;   // tq = fma(x, rstd, nms)

    // ---- pass 2: gelu(tq*G + B), pack bf16 ----
    int4 pC[4];
    #pragma unroll
    for (int ks = 0; ks < 4; ++ks) {
      const int off = ks * 32 + g * 8;
      float4 g0 = *(const float4*)(sG + off);
      float4 g1 = *(const float4*)(sG + off + 4);
      float4 b0 = *(const float4*)(sB + off);
      float4 b1 = *(const float4*)(sB + off + 4);
      float gg[8] = {g0.x,g0.y,g0.z,g0.w,g1.x,g1.y,g1.z,g1.w};
      float bb[8] = {b0.x,b0.y,b0.z,b0.w,b1.x,b1.y,b1.z,b1.w};
      float y[8];
      #pragma unroll
      for (int q = 0; q < 8; ++q) {
        float tq = __builtin_fmaf(xc[ks][q], rstd, nms);
        y[q] = geluf(__builtin_fmaf(tq, gg[q], bb[q]));
      }
      pC[ks].x = pk_bf16(y[0], y[1]); pC[ks].y = pk_bf16(y[2], y[3]);
      pC[ks].z = pk_bf16(y[4], y[5]); pC[ks].w = pk_bf16(y[6], y[7]);
    }

    // ---- layer-2 GEMMs via MFMA (cons bf16, assoc f16) ----
    f32x4 accC[4] = {zero, zero, zero, zero};
    f32x4 accA[2] = {zero, zero};
    #pragma unroll
    for (int ks = 0; ks < 4; ++ks) {
      bf16x8 aC = __builtin_bit_cast(bf16x8, pC[ks]);
      #pragma unroll
      for (int nt = 0; nt < 4; ++nt)
        accC[nt] = __builtin_amdgcn_mfma_f32_16x16x32_bf16(
            aC, bfr[(nt * 4 + ks) * 64 + lane], accC[nt], 0, 0, 0);
      #pragma unroll
      for (int nt = 0; nt < 2; ++nt)
        accA[nt] = __builtin_amdgcn_mfma_f32_16x16x32_f16(
            pA[ks], bfrA[(nt * 4 + ks) * 64 + lane], accA[nt], 0, 0, 0);
    }

    // ---- layer 3: bias + act + dot W3; DPP 16-lane reduction ----
    float sc[4] = {0.f, 0.f, 0.f, 0.f};
    float sa[4] = {0.f, 0.f, 0.f, 0.f};
    #pragma unroll
    for (int nt = 0; nt < 4; ++nt)
      #pragma unroll
      for (int r = 0; r < 4; ++r)
        sc[r] = __builtin_fmaf(geluf(accC[nt][r] + cb2v[nt]), cw3v[nt], sc[r]);
    #pragma unroll
    for (int nt = 0; nt < 2; ++nt)
      #pragma unroll
      for (int r = 0; r < 4; ++r)
        sa[r] = __builtin_fmaf(fmaxf(accA[nt][r] + ab2v[nt], 0.f), aw3v[nt], sa[r]);
    #pragma unroll
    for (int r = 0; r < 4; ++r) { sc[r] = red16(sc[r]); sa[r] = red16(sa[r]); }

    if (m < 4) {
      const int jr = jt_cur * 64 + wave * 16 + g * 4 + m;
      if (jr > i) {
        const int p = i * (2 * N_TR - i - 1) / 2 + (jr - i - 1);
        out[p]           = sigmoidf_(sc[m] + cb3s);
        out[P_PAIRS + p] = sigmoidf_(sa[m] + ab3s);
      }
    }
  }
}

extern "C" void kernel_launch(void* const* d_in, const int* in_sizes, int n_in,
                              void* d_out, int out_size, void* d_ws, size_t ws_size,
                              hipStream_t stream) {
  const float* emb = (const float*)d_in[0];
  const float* tf  = (const float*)d_in[1];
  const float* cW1 = (const float*)d_in[2];
  const float* cb1 = (const float*)d_in[3];
  const float* lng = (const float*)d_in[4];
  const float* lnb = (const float*)d_in[5];
  const float* cW2 = (const float*)d_in[6];
  const float* cb2 = (const float*)d_in[7];
  const float* cW3 = (const float*)d_in[8];
  const float* cb3 = (const float*)d_in[9];
  const float* aW1 = (const float*)d_in[10];
  const float* ab1 = (const float*)d_in[11];
  const float* aW2 = (const float*)d_in[12];
  const float* ab2 = (const float*)d_in[13];
  const float* aW3 = (const float*)d_in[14];
  const float* ab3 = (const float*)d_in[15];
  const float* iW1 = (const float*)d_in[16];
  const float* ib1 = (const float*)d_in[17];
  const float* iW2 = (const float*)d_in[18];
  const float* ib2 = (const float*)d_in[19];

  float* ws = (float*)d_ws;
  unsigned short* wsH = (unsigned short*)d_ws;
  unsigned short* frag = (unsigned short*)((char*)d_ws + WS_FRAG_BYTES);
  float* out = (float*)d_out;

  hipLaunchKernelGGL(k_pre, dim3(816), dim3(256), 0, stream,
                     emb, tf, cW1, cb1, aW1, ab1, cW2, aW2,
                     iW1, ib1, iW2, ib2, ws, wsH, frag, out);
  hipLaunchKernelGGL(k_pairs, dim3(1024), dim3(256), 0, stream,
                     ws, wsH, frag, lng, lnb, cb2, cW3, cb3, ab2, aW3, ab3, out);
}

// Round 13
// 166.049 us; speedup vs baseline: 2.0087x; 1.0080x over previous
//
#include <hip/hip_runtime.h>

#define N_TR 1024
#define H_DIM 128
#define P_PAIRS 523776   // N*(N-1)/2
#define N_UNITS 8688     // sum over jt<16 of (64*jt+63); C(jt)=32jt^2+31jt
#define MAX_SLOTS 9
// ws float offsets (f32 regions)
#define WS_U    0
#define WS_V    131072
#define WS_SUMU 393216   // per i: {sumU, sumU2} (cons net)
#define WS_SUMV 395264   // per j: {sumV, sumV2} (cons net, V includes bias)
// ws ushort offsets (f16 regions)
#define WS_UAH  524288   // Ua as f16, 1024x128
#define WS_VAH  655360   // Va as f16 (incl bias), 1024x128
// ws byte offsets
#define WS_FRAG_BYTES 1589248u  // 12288 ushorts: [0,8192) cons bf16, [8192,12288) assoc f16

typedef __attribute__((ext_vector_type(8))) short bf16x8;
typedef __attribute__((ext_vector_type(8))) _Float16 h16x8;
typedef __attribute__((ext_vector_type(4))) float f32x4;

__device__ __forceinline__ short f2bfs(float f) {
  unsigned x = __float_as_uint(f);
  unsigned r = x + 0x7fffu + ((x >> 16) & 1u);
  return (short)(r >> 16);
}
__device__ __forceinline__ unsigned short f2h(float f) {
  _Float16 h = (_Float16)f;
  return __builtin_bit_cast(unsigned short, h);
}
// pack two f32 -> two bf16 in one word (validated R2-R11)
__device__ __forceinline__ unsigned pk_bf16(float f0, float f1) {
  unsigned a0 = __float_as_uint(f0) + 0x8000u;
  unsigned a1 = __float_as_uint(f1) + 0x8000u;
  return __builtin_amdgcn_perm(a1, a0, 0x07060302u);
}
// branch-free tanh-form GELU (validated: absmax 0.0039 total)
__device__ __forceinline__ float geluf(float x) {
  float u = x * x;
  float p = __builtin_fmaf(u, 0.10294324f, 2.30220820f);
  float e = __builtin_amdgcn_exp2f(x * p);
  float r = __builtin_amdgcn_rcpf(e + 1.0f);
  return __builtin_fmaf(-x, r, x);
}
__device__ __forceinline__ float sigmoidf_(float x) {
  float e = __builtin_amdgcn_exp2f(x * -1.4426950408889634f);
  return __builtin_amdgcn_rcpf(1.0f + e);
}
// 16-lane DPP sum reduction on the VALU pipe (validated R5-R11)
template <int CTRL>
__device__ __forceinline__ float dpp_add(float x) {
  int v = __builtin_amdgcn_update_dpp(0, __float_as_int(x), CTRL, 0xf, 0xf, true);
  return x + __int_as_float(v);
}
__device__ __forceinline__ float red16(float x) {
  x = dpp_add<0xB1>(x);
  x = dpp_add<0x4E>(x);
  x = dpp_add<0x141>(x);
  x = dpp_add<0x140>(x);
  return x;
}
// decode unit -> jt; C(jt) = 32jt^2 + 31jt
__device__ __forceinline__ int jt_from_u(int u) {
  float f = (sqrtf(961.0f + 128.0f * (float)u) - 31.0f) * 0.015625f;
  int jt = (int)f;
  if (jt > 15) jt = 15;
  while (jt < 15 && 32 * (jt + 1) * (jt + 1) + 31 * (jt + 1) <= u) ++jt;
  while (jt > 0 && 32 * jt * jt + 31 * jt > u) --jt;
  return jt;
}

// ================= K_PRE: fused {uv+sums | repack | imp} ===================
// grid 816: [0,512) uv (2 rows/block), [512,560) repack, [560,816) imp
__global__ __launch_bounds__(256) void k_pre(
    const float* __restrict__ emb, const float* __restrict__ tf,
    const float* __restrict__ cW1, const float* __restrict__ cb1,
    const float* __restrict__ aW1, const float* __restrict__ ab1,
    const float* __restrict__ cW2, const float* __restrict__ aW2,
    const float* __restrict__ iW1, const float* __restrict__ ib1,
    const float* __restrict__ iW2, const float* __restrict__ ib2,
    float* __restrict__ ws, unsigned short* __restrict__ wsH,
    unsigned short* __restrict__ frag, float* __restrict__ out)
{
  __shared__ __align__(16) float sE[2][128];
  __shared__ float sRed[2][8];
  const int blk = blockIdx.x;
  const int t = threadIdx.x;
  const int lane = t & 63, wave = t >> 6;

  if (blk < 512) {
    const int b = blk;
    { int r = t >> 7, c = t & 127; sE[r][c] = emb[(b * 2 + r) * 128 + c]; }
    __syncthreads();
    const int k = t & 127;
    const bool cons = (t < 128);
    const float* W    = cons ? cW1 : aW1;
    const float* bias = cons ? cb1 : ab1;
    float accU0 = 0.f, accU1 = 0.f, accV0 = 0.f, accV1 = 0.f;
    for (int c = 0; c < 128; ++c) {
      float wt = W[c * 128 + k];
      float wb = W[(128 + c) * 128 + k];
      float e0 = sE[0][c], e1 = sE[1][c];
      accU0 = __builtin_fmaf(e0, wt, accU0);
      accU1 = __builtin_fmaf(e1, wt, accU1);
      accV0 = __builtin_fmaf(e0, wb, accV0);
      accV1 = __builtin_fmaf(e1, wb, accV1);
    }
    const float bv = bias[k];
    const float vb0 = accV0 + bv, vb1 = accV1 + bv;
    if (cons) {
      ws[WS_U + (b * 2 + 0) * 128 + k] = accU0;
      ws[WS_U + (b * 2 + 1) * 128 + k] = accU1;
      ws[WS_V + (b * 2 + 0) * 128 + k] = vb0;
      ws[WS_V + (b * 2 + 1) * 128 + k] = vb1;
      float vals[8] = {accU0, accU0 * accU0, accU1, accU1 * accU1,
                       vb0, vb0 * vb0, vb1, vb1 * vb1};
      #pragma unroll
      for (int msk = 1; msk <= 32; msk <<= 1)
        #pragma unroll
        for (int v = 0; v < 8; ++v) vals[v] += __shfl_xor(vals[v], msk, 64);
      if ((t & 63) == 0)
        #pragma unroll
        for (int v = 0; v < 8; ++v) sRed[t >> 6][v] = vals[v];
    } else {
      wsH[WS_UAH + (b * 2 + 0) * 128 + k] = f2h(accU0);
      wsH[WS_UAH + (b * 2 + 1) * 128 + k] = f2h(accU1);
      wsH[WS_VAH + (b * 2 + 0) * 128 + k] = f2h(vb0);
      wsH[WS_VAH + (b * 2 + 1) * 128 + k] = f2h(vb1);
    }
    __syncthreads();
    if (t == 0) {
      const int i0 = b * 2;
      ws[WS_SUMU + i0 * 2 + 0]       = sRed[0][0] + sRed[1][0];
      ws[WS_SUMU + i0 * 2 + 1]       = sRed[0][1] + sRed[1][1];
      ws[WS_SUMU + (i0 + 1) * 2 + 0] = sRed[0][2] + sRed[1][2];
      ws[WS_SUMU + (i0 + 1) * 2 + 1] = sRed[0][3] + sRed[1][3];
      ws[WS_SUMV + i0 * 2 + 0]       = sRed[0][4] + sRed[1][4];
      ws[WS_SUMV + i0 * 2 + 1]       = sRed[0][5] + sRed[1][5];
      ws[WS_SUMV + (i0 + 1) * 2 + 0] = sRed[0][6] + sRed[1][6];
      ws[WS_SUMV + (i0 + 1) * 2 + 1] = sRed[0][7] + sRed[1][7];
    }
  } else if (blk < 560) {
    int u = (blk - 512) * 256 + t;   // 0..12287
    if (u < 8192) {   // cons frags: bf16
      int j = u & 7, ln = (u >> 3) & 63, ks = (u >> 9) & 3, nt = u >> 11;
      frag[u] = (unsigned short)f2bfs(cW2[(ks * 32 + (ln >> 4) * 8 + j) * 64 + nt * 16 + (ln & 15)]);
    } else {          // assoc frags: f16
      int v = u - 8192;
      int j = v & 7, ln = (v >> 3) & 63, ks = (v >> 9) & 3, nt = v >> 11;
      frag[u] = f2h(aW2[(ks * 32 + (ln >> 4) * 8 + j) * 32 + nt * 16 + (ln & 15)]);
    }
  } else {
    const int r = (blk - 560) * 4 + wave;
    float acc = 0.f;
    for (int c = 0; c < 128; ++c)
      acc = __builtin_fmaf(emb[r * 128 + c], iW1[c * 64 + lane], acc);
    #pragma unroll
    for (int c = 0; c < 5; ++c)
      acc = __builtin_fmaf(tf[r * 5 + c], iW1[(128 + c) * 64 + lane], acc);
    float d = geluf(acc + ib1[lane]) * iW2[lane];
    #pragma unroll
    for (int msk = 32; msk; msk >>= 1) d += __shfl_xor(d, msk, 64);
    if (lane == 0) out[2 * P_PAIRS + r] = sigmoidf_(d + ib2[0]);
  }
}

// ================= K_PAIRS (two 4-wave teams per block, 32 waves/CU) ======
// Grid 1024 x 512 threads = 8192 waves (8/SIMD at VGPR<=64, 4 blocks/CU by
// LDS 32.7KB) — double R11's TLP at identical total work. Block b owns units
// [543b>>6, 543(b+1)>>6) (8-9); team = wave>>2 takes its half (<=5 iters).
// __launch_bounds__(512,4): VGPR cap 128 — the proven no-spill regime
// (caps <128 demote vC to global reloads; R8-R10 post-mortems).
// R12 bug fixed here: sFrag copy is 1536 uint4 = 3 iters x 512 threads
// (R12's q<6 wrote 2x out of bounds -> core dump).
__global__ __launch_bounds__(512, 4) void k_pairs(
    const float* __restrict__ ws, const unsigned short* __restrict__ wsH,
    const unsigned short* __restrict__ frag,
    const float* __restrict__ lng, const float* __restrict__ lnb,
    const float* __restrict__ cb2, const float* __restrict__ cW3,
    const float* __restrict__ cb3,
    const float* __restrict__ ab2, const float* __restrict__ aW3,
    const float* __restrict__ ab3,
    float* __restrict__ out)
{
  __shared__ __align__(16) unsigned short sFrag[12288];         // 24576 B
  __shared__ __align__(16) float sU[MAX_SLOTS][128];            // 4608 B
  __shared__ __align__(16) unsigned short sUaH[MAX_SLOTS][128]; // 2304 B
  __shared__ __align__(16) float sG[128];                       // 512 B
  __shared__ __align__(16) float sB[128];                       // 512 B
  __shared__ float sSt[MAX_SLOTS * 2];                          // 72 B
  __shared__ int sJt[MAX_SLOTS], sI[MAX_SLOTS];                 // 72 B
  const int t = threadIdx.x;
  const int b = blockIdx.x;
  const int u0 = (543 * b) >> 6;
  const int u1 = (543 * (b + 1)) >> 6;
  const int n  = u1 - u0;          // 8 or 9

  {
    const uint4* src = (const uint4*)frag;
    uint4* dst = (uint4*)sFrag;
    #pragma unroll
    for (int q = 0; q < 3; ++q) dst[t + q * 512] = src[t + q * 512];
  }
  if (t < n) {
    int u = u0 + t;
    int jtu = jt_from_u(u);
    sJt[t] = jtu;
    sI[t]  = u - (32 * jtu * jtu + 31 * jtu);
  }
  for (int s = t >> 5; s < n; s += 16) {
    int u = u0 + s;
    int jtu = jt_from_u(u);
    int iu = u - (32 * jtu * jtu + 31 * jtu);
    int c4 = (t & 31) * 4;
    *(float4*)&sU[s][c4] = *(const float4*)(ws + WS_U + iu * 128 + c4);
    *(ushort4*)&sUaH[s][c4] = *(const ushort4*)(wsH + WS_UAH + iu * 128 + c4);
  }
  if (t < 2 * n) {
    int s = t >> 1;
    int u = u0 + s;
    int jtu = jt_from_u(u);
    int iu = u - (32 * jtu * jtu + 31 * jtu);
    sSt[t] = ws[WS_SUMU + iu * 2 + (t & 1)];
  }
  if (t < 128) { sG[t] = lng[t]; sB[t] = lnb[t]; }
  __syncthreads();

  const int lane = t & 63;
  const int wave = t >> 6;
  const int team = wave >> 2;         // 0 or 1
  const int wv   = wave & 3;          // wave-in-team: j-quarter
  const int m = lane & 15;
  const int g = lane >> 4;
  const int nh = (n + 1) >> 1;
  const int s_begin = team ? nh : 0;
  const int s_end   = team ? n  : nh;

  float cb2v[4], cw3v[4], ab2v[2], aw3v[2];
  #pragma unroll
  for (int nt = 0; nt < 4; ++nt) { cb2v[nt] = cb2[nt * 16 + m]; cw3v[nt] = cW3[nt * 16 + m]; }
  #pragma unroll
  for (int nt = 0; nt < 2; ++nt) { ab2v[nt] = ab2[nt * 16 + m]; aw3v[nt] = aW3[nt * 16 + m]; }
  const float cb3s = cb3[0], ab3s = ab3[0];
  const bf16x8* bfr  = (const bf16x8*)sFrag;          // cons frags [0,1024)
  const h16x8*  bfrA = (const h16x8*)sFrag + 1024;    // assoc frags
  const f32x4 zero = {0.f, 0.f, 0.f, 0.f};
  const h16x8 hzero = {0, 0, 0, 0, 0, 0, 0, 0};
  const float inv128 = 0.0078125f;

  int jt_cur = -1;
  float svj = 0.f, qvj = 0.f;
  float vC[4][8];
  h16x8 vAh[4];

  for (int s = s_begin; s < s_end; ++s) {
    const int jtu = sJt[s];
    const int i   = sI[s];
    if (jtu != jt_cur) {            // team-uniform; rare
      jt_cur = jtu;
      const int j = jtu * 64 + wv * 16 + m;
      const float* Vrow = ws + WS_V + j * 128;
      #pragma unroll
      for (int ks = 0; ks < 4; ++ks) {
        const int off = ks * 32 + g * 8;
        float4 a0 = *(const float4*)(Vrow + off);
        float4 a1 = *(const float4*)(Vrow + off + 4);
        vC[ks][0]=a0.x; vC[ks][1]=a0.y; vC[ks][2]=a0.z; vC[ks][3]=a0.w;
        vC[ks][4]=a1.x; vC[ks][5]=a1.y; vC[ks][6]=a1.z; vC[ks][7]=a1.w;
        vAh[ks] = *(const h16x8*)(wsH + WS_VAH + j * 128 + off);
      }
      svj = ws[WS_SUMV + j * 2];
      qvj = ws[WS_SUMV + j * 2 + 1];
    }
    if (jt_cur * 64 + wv * 16 + 15 <= i) continue;   // wave-uniform skip

    const float* su_row = sU[s];

    // ---- pass 1: x = U+V (regs), fused dot = sum(U*V) ----
    float xc[4][8];
    float d = 0.f;
    #pragma unroll
    for (int ks = 0; ks < 4; ++ks) {
      const int off = ks * 32 + g * 8;
      float4 u0v = *(const float4*)(su_row + off);
      float4 u1v = *(const float4*)(su_row + off + 4);
      float us[8] = {u0v.x,u0v.y,u0v.z,u0v.w,u1v.x,u1v.y,u1v.z,u1v.w};
      #pragma unroll
      for (int q = 0; q < 8; ++q) {
        xc[ks][q] = us[q] + vC[ks][q];
        d = __builtin_fmaf(us[q], vC[ks][q], d);
      }
    }
    d += __shfl_xor(d, 16, 64);
    d += __shfl_xor(d, 32, 64);

    // ---- assoc phase 1 (f16 packed; overlaps shfl latency) ----
    h16x8 pA[4];
    #pragma unroll
    for (int ks = 0; ks < 4; ++ks) {
      const int off = ks * 32 + g * 8;
      h16x8 ua = *(const h16x8*)&sUaH[s][off];
      pA[ks] = __builtin_elementwise_max(ua + vAh[ks], hzero);
    }

    const float su = sSt[s * 2], qu = sSt[s * 2 + 1];
    const float mean = (su + svj) * inv128;
    const float ex2  = __builtin_fmaf(2.f, d, qu + qvj) * inv128;
    const float var  = ex2 - mean * mean;
    const float rstd = rsqrtf(var + 1e-5f);
    const float nms  = -mean * rstd;   // tq = fma(x, rstd, nms)

    // ---- pass 2: gelu(tq*G + B), pack bf16 ----
    int4 pC[4];
    #pragma unroll
    for (int ks = 0; ks < 4; ++ks) {
      const int off = ks * 32 + g * 8;
      float4 g0 = *(const float4*)(sG + off);
      float4 g1 = *(const float4*)(sG + off + 4);
      float4 b0 = *(const float4*)(sB + off);
      float4 b1 = *(const float4*)(sB + off + 4);
      float gg[8] = {g0.x,g0.y,g0.z,g0.w,g1.x,g1.y,g1.z,g1.w};
      float bb[8] = {b0.x,b0.y,b0.z,b0.w,b1.x,b1.y,b1.z,b1.w};
      float y[8];
      #pragma unroll
      for (int q = 0; q < 8; ++q) {
        float tq = __builtin_fmaf(xc[ks][q], rstd, nms);
        y[q] = geluf(__builtin_fmaf(tq, gg[q], bb[q]));
      }
      pC[ks].x = pk_bf16(y[0], y[1]); pC[ks].y = pk_bf16(y[2], y[3]);
      pC[ks].z = pk_bf16(y[4], y[5]); pC[ks].w = pk_bf16(y[6], y[7]);
    }

    // ---- layer-2 GEMMs via MFMA (cons bf16, assoc f16) ----
    f32x4 accC[4] = {zero, zero, zero, zero};
    f32x4 accA[2] = {zero, zero};
    #pragma unroll
    for (int ks = 0; ks < 4; ++ks) {
      bf16x8 aC = __builtin_bit_cast(bf16x8, pC[ks]);
      #pragma unroll
      for (int nt = 0; nt < 4; ++nt)
        accC[nt] = __builtin_amdgcn_mfma_f32_16x16x32_bf16(
            aC, bfr[(nt * 4 + ks) * 64 + lane], accC[nt], 0, 0, 0);
      #pragma unroll
      for (int nt = 0; nt < 2; ++nt)
        accA[nt] = __builtin_amdgcn_mfma_f32_16x16x32_f16(
            pA[ks], bfrA[(nt * 4 + ks) * 64 + lane], accA[nt], 0, 0, 0);
    }

    // ---- layer 3: bias + act + dot W3; DPP 16-lane reduction ----
    float sc[4] = {0.f, 0.f, 0.f, 0.f};
    float sa[4] = {0.f, 0.f, 0.f, 0.f};
    #pragma unroll
    for (int nt = 0; nt < 4; ++nt)
      #pragma unroll
      for (int r = 0; r < 4; ++r)
        sc[r] = __builtin_fmaf(geluf(accC[nt][r] + cb2v[nt]), cw3v[nt], sc[r]);
    #pragma unroll
    for (int nt = 0; nt < 2; ++nt)
      #pragma unroll
      for (int r = 0; r < 4; ++r)
        sa[r] = __builtin_fmaf(fmaxf(accA[nt][r] + ab2v[nt], 0.f), aw3v[nt], sa[r]);
    #pragma unroll
    for (int r = 0; r < 4; ++r) { sc[r] = red16(sc[r]); sa[r] = red16(sa[r]); }

    if (m < 4) {
      const int jr = jt_cur * 64 + wv * 16 + g * 4 + m;
      if (jr > i) {
        const int p = i * (2 * N_TR - i - 1) / 2 + (jr - i - 1);
        out[p]           = sigmoidf_(sc[m] + cb3s);
        out[P_PAIRS + p] = sigmoidf_(sa[m] + ab3s);
      }
    }
  }
}

extern "C" void kernel_launch(void* const* d_in, const int* in_sizes, int n_in,
                              void* d_out, int out_size, void* d_ws, size_t ws_size,
                              hipStream_t stream) {
  const float* emb = (const float*)d_in[0];
  const float* tf  = (const float*)d_in[1];
  const float* cW1 = (const float*)d_in[2];
  const float* cb1 = (const float*)d_in[3];
  const float* lng = (const float*)d_in[4];
  const float* lnb = (const float*)d_in[5];
  const float* cW2 = (const float*)d_in[6];
  const float* cb2 = (const float*)d_in[7];
  const float* cW3 = (const float*)d_in[8];
  const float* cb3 = (const float*)d_in[9];
  const float* aW1 = (const float*)d_in[10];
  const float* ab1 = (const float*)d_in[11];
  const float* aW2 = (const float*)d_in[12];
  const float* ab2 = (const float*)d_in[13];
  const float* aW3 = (const float*)d_in[14];
  const float* ab3 = (const float*)d_in[15];
  const float* iW1 = (const float*)d_in[16];
  const float* ib1 = (const float*)d_in[17];
  const float* iW2 = (const float*)d_in[18];
  const float* ib2 = (const float*)d_in[19];

  float* ws = (float*)d_ws;
  unsigned short* wsH = (unsigned short*)d_ws;
  unsigned short* frag = (unsigned short*)((char*)d_ws + WS_FRAG_BYTES);
  float* out = (float*)d_out;

  hipLaunchKernelGGL(k_pre, dim3(816), dim3(256), 0, stream,
                     emb, tf, cW1, cb1, aW1, ab1, cW2, aW2,
                     iW1, ib1, iW2, ib2, ws, wsH, frag, out);
  hipLaunchKernelGGL(k_pairs, dim3(1024), dim3(512), 0, stream,
                     ws, wsH, frag, lng, lnb, cb2, cW3, cb3, ab2, aW3, ab3, out);
}